// Round 5
// baseline (16044.511 us; speedup 1.0000x reference)
//
#include <hip/hip_runtime.h>
#include <math.h>

#define B   256
#define LT  128
#define LP  64
#define DM  512
#define D3  1536
#define DPH 80
#define SCALE_F 0.044194173824159216f   // 1/sqrt(512)

__device__ __forceinline__ float dot4(float4 a, float4 b) {
    return a.x*b.x + a.y*b.y + a.z*b.z + a.w*b.w;
}
__device__ __forceinline__ float sigmoidf_(float x) {
    return 1.0f / (1.0f + expf(-x));
}

// Ticket grid barrier: monotone counter, agent-scope acq/rel (emits the
// cross-XCD wbl2/inv cache ops). Counter must be zeroed before launch.
__device__ __forceinline__ void grid_barrier(int* bar, int nblk) {
    __syncthreads();
    if (threadIdx.x == 0) {
        int ticket = __hip_atomic_fetch_add(bar, 1, __ATOMIC_ACQ_REL,
                                            __HIP_MEMORY_SCOPE_AGENT);
        int target = (ticket / nblk + 1) * nblk;
        while (__hip_atomic_load(bar, __ATOMIC_ACQUIRE,
                                 __HIP_MEMORY_SCOPE_AGENT) < target)
            __builtin_amdgcn_s_sleep(8);
    }
    __syncthreads();
}

// ---------------------------------------------------------------------------
// Precompute G[r][n] = bias[n] + sum_j Emb[r][j] * W[n*wstride + woff + j]
// ---------------------------------------------------------------------------
__global__ __launch_bounds__(256) void precompG_kernel(
    const float* __restrict__ Emb, const float* __restrict__ W,
    const float* __restrict__ bias, float* __restrict__ G,
    int wstride, int woff)
{
    const int n  = blockIdx.x * 256 + threadIdx.x;
    const int r0 = blockIdx.y * 4;
    __shared__ float es[4][DM];
    for (int i = threadIdx.x; i < 4 * DM; i += 256)
        es[i >> 9][i & 511] = Emb[(r0 + (i >> 9)) * DM + (i & 511)];
    __syncthreads();
    float acc[4] = {0.f, 0.f, 0.f, 0.f};
    const float* wr = &W[(size_t)n * wstride + woff];
    for (int j = 0; j < DM; j += 4) {
        float4 w4 = *(const float4*)&wr[j];
        #pragma unroll
        for (int rr = 0; rr < 4; ++rr) {
            float4 e4 = *(const float4*)&es[rr][j];
            acc[rr] += dot4(e4, w4);
        }
    }
    float bv = bias[n];
    #pragma unroll
    for (int rr = 0; rr < 4; ++rr)
        G[(r0 + rr) * D3 + n] = acc[rr] + bv;
}

// ---------------------------------------------------------------------------
// Persistent encoder: 256 blocks = dir(2) x jblk(32, 16 cols) x bblk(4, 64
// rows). Whh slab LDS-resident (loaded once). 128 steps with grid barriers;
// hpost fused at the end. ~119 KB LDS -> exactly 1 block/CU.
// ---------------------------------------------------------------------------
__global__ __launch_bounds__(256, 1) void enc_persist_kernel(
    const float* __restrict__ Gf, const float* __restrict__ Gb,
    const float* __restrict__ Whh_f, const float* __restrict__ Whh_b,
    const float* __restrict__ bhh_f, const float* __restrict__ bhh_b,
    const int* __restrict__ text,
    float* __restrict__ hF0, float* __restrict__ hF1,
    float* __restrict__ hB0, float* __restrict__ hB1,
    float* __restrict__ E,
    const float* __restrict__ hpost_W, const float* __restrict__ hpost_b,
    float* __restrict__ hd0, int* __restrict__ bar)
{
    __shared__ float Wl[48][516];     // 99 KB weight slab
    __shared__ float As[2][64][36];   // 18.4 KB h staging (dbuf)
    __shared__ float xs[1024];        // hpost staging
    __shared__ float bl[48];

    const int tid  = threadIdx.x;
    const int blk  = blockIdx.x;
    const int dir  = blk & 1;
    const int jblk = (blk >> 1) & 31;
    const int bblk = blk >> 6;
    const int jtile = jblk * 16;
    const int btile = bblk * 64;

    const float* G   = dir ? Gb : Gf;
    const float* Whh = dir ? Whh_b : Whh_f;
    const float* bhh = dir ? bhh_b : bhh_f;
    float* h0 = dir ? hB0 : hF0;
    float* h1 = dir ? hB1 : hF1;
    const int yoff = dir ? DM : 0;

    // one-time weight slab load: lds row r -> gate g=r>>4, col j=jtile+(r&15)
    for (int i = tid; i < 48 * 128; i += 256) {
        const int r = i >> 7, c = (i & 127) << 2;
        const int g = r >> 4, j = jtile + (r & 15);
        *(float4*)&Wl[r][c] =
            *(const float4*)&Whh[(size_t)(g * DM + j) * DM + c];
    }
    if (tid < 48) bl[tid] = bhh[(tid >> 4) * DM + jtile + (tid & 15)];
    __syncthreads();

    const int jj   = tid & 15;       // j lane
    const int rg   = tid >> 4;       // 16 row groups x 4 rows
    const int lrow = tid >> 2;       // staging row 0..63
    const int lcol = (tid & 3) * 8;  // staging col (2 float4)

    for (int s = 0; s < LT; ++s) {
        const int t = dir ? (LT - 1 - s) : s;
        const float* hin = (s & 1) ? h1 : h0;
        float* hout      = (s & 1) ? h0 : h1;

        float acc[4][3];
        #pragma unroll
        for (int m = 0; m < 4; ++m) {
            acc[m][0] = 0.f; acc[m][1] = 0.f; acc[m][2] = 0.f;
        }

        float4 rA0 = *(const float4*)&hin[(btile + lrow) * DM + lcol];
        float4 rA1 = *(const float4*)&hin[(btile + lrow) * DM + lcol + 4];
        int buf = 0;
        for (int kc = 0; kc < 16; ++kc) {
            *(float4*)&As[buf][lrow][lcol]     = rA0;
            *(float4*)&As[buf][lrow][lcol + 4] = rA1;
            __syncthreads();
            if (kc < 15) {
                const int k0 = (kc + 1) * 32;
                rA0 = *(const float4*)&hin[(btile + lrow) * DM + k0 + lcol];
                rA1 = *(const float4*)&hin[(btile + lrow) * DM + k0 + lcol + 4];
            }
            const int kb = kc * 32;
            #pragma unroll
            for (int c4 = 0; c4 < 8; ++c4) {
                float4 bv0 = *(float4*)&Wl[jj][kb + c4 * 4];
                float4 bv1 = *(float4*)&Wl[16 + jj][kb + c4 * 4];
                float4 bv2 = *(float4*)&Wl[32 + jj][kb + c4 * 4];
                #pragma unroll
                for (int m = 0; m < 4; ++m) {
                    float4 av = *(float4*)&As[buf][rg * 4 + m][c4 * 4];
                    acc[m][0] += dot4(av, bv0);
                    acc[m][1] += dot4(av, bv1);
                    acc[m][2] += dot4(av, bv2);
                }
            }
            buf ^= 1;
        }

        const int j = jtile + jj;
        #pragma unroll
        for (int m = 0; m < 4; ++m) {
            const int b = btile + rg * 4 + m;
            const int c = text[b * LT + t];
            float hr = acc[m][0] + bl[jj];
            float hz = acc[m][1] + bl[16 + jj];
            float hn = acc[m][2] + bl[32 + jj];
            float r = sigmoidf_(G[c * D3 + j] + hr);
            float z = sigmoidf_(G[c * D3 + DM + j] + hz);
            float n = tanhf(G[c * D3 + 2 * DM + j] + r * hn);
            float hp = hin[b * DM + j];
            float hv = (1.f - z) * n + z * hp;
            hout[b * DM + j] = hv;
            E[(size_t)(b * LT + t) * 1024 + yoff + j] = hv;
        }
        grid_barrier(bar, 256);
    }

    // fused hpost: block blk -> batch row blk (finals live in hF0/hB0)
    {
        const int b = blk;
        for (int i = tid; i < DM; i += 256) {
            xs[i]      = hF0[b * DM + i];
            xs[DM + i] = hB0[b * DM + i];
        }
        __syncthreads();
        for (int n = tid; n < DM; n += 256) {
            const float* wr = &hpost_W[n * 1024];
            float acc = 0.f;
            for (int jx = 0; jx < 1024; jx += 4)
                acc += dot4(*(const float4*)&xs[jx], *(const float4*)&wr[jx]);
            hd0[b * DM + n] = tanhf(acc + hpost_b[n]);
        }
    }
}

// ---------------------------------------------------------------------------
// Chunked k/v projection (rows [r0, r0+16384)) -> temp T, then copy4 back.
// ---------------------------------------------------------------------------
__global__ __launch_bounds__(256) void kv_chunk_kernel(
    const float* __restrict__ E,
    const float* __restrict__ wk, const float* __restrict__ wv,
    const float* __restrict__ kb, const float* __restrict__ vb,
    float* __restrict__ T, int r0)
{
    __shared__ float As[64][36];
    __shared__ float Bk[64][36];
    __shared__ float Bv[64][36];
    const int tid = threadIdx.x;
    const int nn = tid & 15, bb = tid >> 4;
    const int ntile = blockIdx.x * 64;
    const int mtile = blockIdx.y * 64;

    float ak[4][4], av_[4][4];
    #pragma unroll
    for (int m = 0; m < 4; ++m)
        #pragma unroll
        for (int i = 0; i < 4; ++i) { ak[m][i] = 0.f; av_[m][i] = 0.f; }

    const int lrow = tid >> 3;
    const int lcol = (tid & 7) * 4;

    for (int k0 = 0; k0 < 1024; k0 += 32) {
        __syncthreads();
        *(float4*)&As[lrow][lcol] =
            *(const float4*)&E[(size_t)(r0 + mtile + lrow) * 1024 + k0 + lcol];
        *(float4*)&As[lrow + 32][lcol] =
            *(const float4*)&E[(size_t)(r0 + mtile + lrow + 32) * 1024 + k0 + lcol];
        *(float4*)&Bk[lrow][lcol] =
            *(const float4*)&wk[(ntile + lrow) * 1024 + k0 + lcol];
        *(float4*)&Bk[lrow + 32][lcol] =
            *(const float4*)&wk[(ntile + lrow + 32) * 1024 + k0 + lcol];
        *(float4*)&Bv[lrow][lcol] =
            *(const float4*)&wv[(ntile + lrow) * 1024 + k0 + lcol];
        *(float4*)&Bv[lrow + 32][lcol] =
            *(const float4*)&wv[(ntile + lrow + 32) * 1024 + k0 + lcol];
        __syncthreads();
        #pragma unroll
        for (int c4 = 0; c4 < 8; ++c4) {
            float4 a4[4], k4[4], v4[4];
            #pragma unroll
            for (int m = 0; m < 4; ++m) a4[m] = *(float4*)&As[bb + 16 * m][c4 * 4];
            #pragma unroll
            for (int i = 0; i < 4; ++i) {
                k4[i] = *(float4*)&Bk[nn + 16 * i][c4 * 4];
                v4[i] = *(float4*)&Bv[nn + 16 * i][c4 * 4];
            }
            #pragma unroll
            for (int m = 0; m < 4; ++m)
                #pragma unroll
                for (int i = 0; i < 4; ++i) {
                    ak[m][i]  += dot4(a4[m], k4[i]);
                    av_[m][i] += dot4(a4[m], v4[i]);
                }
        }
    }
    #pragma unroll
    for (int m = 0; m < 4; ++m) {
        const int lm = mtile + bb + 16 * m;
        #pragma unroll
        for (int i = 0; i < 4; ++i) {
            const int gn = ntile + nn + 16 * i;
            T[(size_t)lm * 1024 + gn]       = ak[m][i]  + kb[gn];
            T[(size_t)lm * 1024 + DM + gn]  = av_[m][i] + vb[gn];
        }
    }
}

__global__ __launch_bounds__(256) void copy4_kernel(
    float4* __restrict__ dst, const float4* __restrict__ src, int n4)
{
    int i = blockIdx.x * 256 + threadIdx.x;
    const int stride = gridDim.x * 256;
    for (; i < n4; i += stride) dst[i] = src[i];
}

// ---------------------------------------------------------------------------
// Attend/post body (identical math to previous rounds' kernel).
// ---------------------------------------------------------------------------
__device__ __forceinline__ void attend_body(
    int b, int tid, const float* __restrict__ q, const float* __restrict__ EKV,
    const float* __restrict__ post_W, const float* __restrict__ post_b,
    float* __restrict__ attn, float* __restrict__ res,
    float* __restrict__ a_o, int* __restrict__ dec_i,
    int s, int attn_row, int do_post, int do_attn,
    float* qs, float* part, float* sarr, float* red, float4 (*pvp)[128])
{
    if (tid < 128)
        *(float4*)&qs[tid * 4] = *(const float4*)&q[b * DM + tid * 4];
    __syncthreads();

    if (do_post) {
        if (tid < DPH) {
            const float* wr = &post_W[tid * DM];
            float acc = 0.f;
            for (int d = 0; d < DM; d += 4)
                acc += dot4(*(const float4*)&qs[d], *(const float4*)&wr[d]);
            float lv = acc + post_b[tid];
            res[(size_t)(b * LP + s) * DPH + tid] = lv;
            part[tid] = lv;
        }
        __syncthreads();
        if (tid == 0) {   // first-occurrence argmax, matching jnp.argmax
            float best = part[0]; int bi = 0;
            for (int p = 1; p < DPH; ++p) {
                float vv = part[p];
                if (vv > best) { best = vv; bi = p; }
            }
            dec_i[b] = bi;
        }
        __syncthreads();
    }

    if (do_attn) {
        {
            const int r = tid & 127, half = tid >> 7;
            const float* kr = &EKV[(size_t)(b * LT + r) * 1024 + half * 256];
            const float* qh = &qs[half * 256];
            float p = 0.f;
            #pragma unroll
            for (int d = 0; d < 256; d += 4)
                p += dot4(*(const float4*)&qh[d], *(const float4*)&kr[d]);
            part[tid] = p;
        }
        __syncthreads();
        if (tid < LT) sarr[tid] = (part[tid] + part[tid + 128]) * SCALE_F;
        __syncthreads();
        if (tid < 64) {
            float m = fmaxf(sarr[tid], sarr[tid + 64]);
            #pragma unroll
            for (int off = 32; off > 0; off >>= 1)
                m = fmaxf(m, __shfl_xor(m, off));
            if (tid == 0) red[0] = m;
        }
        __syncthreads();
        const float smax = red[0];
        if (tid < LT) sarr[tid] = expf(sarr[tid] - smax);
        __syncthreads();
        if (tid < 64) {
            float ssum = sarr[tid] + sarr[tid + 64];
            #pragma unroll
            for (int off = 32; off > 0; off >>= 1)
                ssum += __shfl_xor(ssum, off);
            if (tid == 0) red[1] = ssum;
        }
        __syncthreads();
        const float inv = 1.0f / red[1];
        if (tid < LT) {
            float a = sarr[tid] * inv;
            sarr[tid] = a;
            attn[(size_t)(b * LP + attn_row) * LT + tid] = a;
        }
        __syncthreads();
        {
            const int d4 = tid & 127, half = tid >> 7;
            const float* vb0 = &EKV[(size_t)b * LT * 1024 + DM];
            float4 acc = make_float4(0.f, 0.f, 0.f, 0.f);
            const int l0 = half * 64;
            #pragma unroll 8
            for (int l = l0; l < l0 + 64; ++l) {
                float a = sarr[l];
                float4 v4 = *(const float4*)&vb0[(size_t)l * 1024 + d4 * 4];
                acc.x += a * v4.x; acc.y += a * v4.y;
                acc.z += a * v4.z; acc.w += a * v4.w;
            }
            pvp[half][d4] = acc;
        }
        __syncthreads();
        if (tid < 128) {
            float4 p0 = pvp[0][tid], p1 = pvp[1][tid];
            float4 o = make_float4(p0.x + p1.x, p0.y + p1.y,
                                   p0.z + p1.z, p0.w + p1.w);
            *(float4*)&a_o[b * DM + tid * 4] = o;
        }
    }
}

// ---------------------------------------------------------------------------
// Persistent decoder: 256 blocks = jblk(64, 8 cols) x bblk(4, 64 rows).
// Wih-half + Whh slabs LDS-resident. Per step: GRU phase | barrier |
// attend+post phase (block b -> row b) | barrier. ~122 KB LDS -> 1 block/CU.
// ---------------------------------------------------------------------------
__global__ __launch_bounds__(256, 1) void dec_persist_kernel(
    const float* __restrict__ Gd,
    const float* __restrict__ dec_Wih, const float* __restrict__ dec_Whh,
    const float* __restrict__ dec_bhh,
    const float* __restrict__ EKV,
    const float* __restrict__ post_W, const float* __restrict__ post_b,
    float* __restrict__ attn, float* __restrict__ res,
    float* __restrict__ a_o, int* __restrict__ dec_i,
    float* __restrict__ hd0, float* __restrict__ hd1,
    int* __restrict__ bar)
{
    __shared__ float Wi[24][516];
    __shared__ float Wh[24][516];
    __shared__ float As[2][64][36];
    __shared__ float bl[24];
    __shared__ float qs[DM];
    __shared__ float part[256];
    __shared__ float sarr[LT];
    __shared__ float red[2];
    __shared__ float4 pvp[2][128];

    const int tid  = threadIdx.x;
    const int blk  = blockIdx.x;
    const int jblk = blk & 63;
    const int bblk = blk >> 6;
    const int jtile = jblk * 8;
    const int btile = bblk * 64;

    for (int i = tid; i < 24 * 128; i += 256) {
        const int r = i >> 7, c = (i & 127) << 2;
        const int g = r >> 3, j = jtile + (r & 7);
        *(float4*)&Wi[r][c] =
            *(const float4*)&dec_Wih[(size_t)(g * DM + j) * 1024 + DM + c];
        *(float4*)&Wh[r][c] =
            *(const float4*)&dec_Whh[(size_t)(g * DM + j) * DM + c];
    }
    if (tid < 24) bl[tid] = dec_bhh[(tid >> 3) * DM + jtile + (tid & 7)];
    __syncthreads();

    // initial attend: q = hd0 -> attn row 0 + a_o
    attend_body(blk, tid, hd0, EKV, post_W, post_b, attn, res, a_o, dec_i,
                0, 0, 0, 1, qs, part, sarr, red, pvp);
    grid_barrier(bar, 256);

    const int jj   = tid & 7;
    const int rg   = tid >> 3;       // 32 row groups x 2 rows
    const int lrow = tid >> 2;
    const int lcol = (tid & 3) * 8;

    for (int s = 0; s < LP; ++s) {
        const float* hin = (s & 1) ? hd1 : hd0;
        float* hout      = (s & 1) ? hd0 : hd1;

        float acc[2][4];   // [row][0:r 1:z 2:inn 3:hn]
        #pragma unroll
        for (int m = 0; m < 2; ++m)
            #pragma unroll
            for (int g = 0; g < 4; ++g) acc[m][g] = 0.f;

        #pragma unroll
        for (int ph = 0; ph < 2; ++ph) {
            const float* Aptr = (ph == 0) ? a_o : hin;
            const float (*W)[516] = (ph == 0) ? Wi : Wh;

            float4 rA0 = *(const float4*)&Aptr[(btile + lrow) * DM + lcol];
            float4 rA1 = *(const float4*)&Aptr[(btile + lrow) * DM + lcol + 4];
            int buf = 0;
            for (int kc = 0; kc < 16; ++kc) {
                *(float4*)&As[buf][lrow][lcol]     = rA0;
                *(float4*)&As[buf][lrow][lcol + 4] = rA1;
                __syncthreads();
                if (kc < 15) {
                    const int k0 = (kc + 1) * 32;
                    rA0 = *(const float4*)&Aptr[(btile + lrow) * DM + k0 + lcol];
                    rA1 = *(const float4*)&Aptr[(btile + lrow) * DM + k0 + lcol + 4];
                }
                const int kb = kc * 32;
                #pragma unroll
                for (int c4 = 0; c4 < 8; ++c4) {
                    float4 bv0 = *(float4*)&W[jj][kb + c4 * 4];
                    float4 bv1 = *(float4*)&W[8 + jj][kb + c4 * 4];
                    float4 bv2 = *(float4*)&W[16 + jj][kb + c4 * 4];
                    #pragma unroll
                    for (int m = 0; m < 2; ++m) {
                        float4 av = *(float4*)&As[buf][rg * 2 + m][c4 * 4];
                        acc[m][0]      += dot4(av, bv0);
                        acc[m][1]      += dot4(av, bv1);
                        acc[m][2 + ph] += dot4(av, bv2);
                    }
                }
                buf ^= 1;
            }
            __syncthreads();
        }

        const int j = jtile + jj;
        #pragma unroll
        for (int m = 0; m < 2; ++m) {
            const int b = btile + rg * 2 + m;
            const int c = dec_i[b];
            float r = sigmoidf_(Gd[c * D3 + j] + bl[jj] + acc[m][0]);
            float z = sigmoidf_(Gd[c * D3 + DM + j] + bl[8 + jj] + acc[m][1]);
            float n = tanhf(Gd[c * D3 + 2 * DM + j] + acc[m][2]
                            + r * (acc[m][3] + bl[16 + jj]));
            float hp = hin[b * DM + j];
            hout[b * DM + j] = (1.f - z) * n + z * hp;
        }
        grid_barrier(bar, 256);

        attend_body(blk, tid, hout, EKV, post_W, post_b, attn, res, a_o, dec_i,
                    s, s + 1, 1, (s < LP - 1) ? 1 : 0,
                    qs, part, sarr, red, pvp);
        grid_barrier(bar, 256);
    }
}

// ---------------------------------------------------------------------------
extern "C" void kernel_launch(void* const* d_in, const int* in_sizes, int n_in,
                              void* d_out, int out_size, void* d_ws, size_t ws_size,
                              hipStream_t stream)
{
    const int*   text    = (const int*)d_in[0];
    const float* E_alpha = (const float*)d_in[2];
    const float* Wih_f   = (const float*)d_in[3];
    const float* Whh_f   = (const float*)d_in[4];
    const float* bih_f   = (const float*)d_in[5];
    const float* bhh_f   = (const float*)d_in[6];
    const float* Wih_b   = (const float*)d_in[7];
    const float* Whh_b   = (const float*)d_in[8];
    const float* bih_b   = (const float*)d_in[9];
    const float* bhh_b   = (const float*)d_in[10];
    const float* hpost_W = (const float*)d_in[11];
    const float* hpost_b = (const float*)d_in[12];
    const float* wk_W    = (const float*)d_in[13];
    const float* wk_b    = (const float*)d_in[14];
    const float* wv_W    = (const float*)d_in[15];
    const float* wv_b    = (const float*)d_in[16];
    const float* E_ph    = (const float*)d_in[17];
    const float* dec_Wih = (const float*)d_in[18];
    const float* dec_Whh = (const float*)d_in[19];
    const float* dec_bih = (const float*)d_in[20];
    const float* dec_bhh = (const float*)d_in[21];
    const float* post_W  = (const float*)d_in[22];
    const float* post_b  = (const float*)d_in[23];

    float* ws = (float*)d_ws;
    float* Gf  = ws;                 // 100*1536
    float* Gb  = Gf  + 153600;
    float* Gd  = Gb  + 153600;       // 80*1536
    float* hF0 = Gd  + 122880;
    float* hF1 = hF0 + 131072;
    float* hB0 = hF1 + 131072;
    float* hB1 = hB0 + 131072;
    float* hd0 = hB1 + 131072;
    float* hd1 = hd0 + 131072;
    float* a_o = hd1 + 131072;
    int*   dec_i = (int*)(a_o + 131072);
    int*   bar   = dec_i + 256;      // bar[0]=enc, bar[1]=dec
    float* E   = a_o + 131072 + 512; // 32768*1024: ys, then in-place K|V
    float* T   = E + 33554432;       // 16384*1024 chunk temp (64 MB)

    hipMemsetAsync(hF0, 0, 131072 * sizeof(float), stream);
    hipMemsetAsync(hB0, 0, 131072 * sizeof(float), stream);
    hipMemsetAsync(dec_i, 0, 258 * sizeof(int), stream);  // dec_i + barriers

    precompG_kernel<<<dim3(6, 25), 256, 0, stream>>>(E_alpha, Wih_f, bih_f, Gf, DM, 0);
    precompG_kernel<<<dim3(6, 25), 256, 0, stream>>>(E_alpha, Wih_b, bih_b, Gb, DM, 0);
    precompG_kernel<<<dim3(6, 20), 256, 0, stream>>>(E_ph, dec_Wih, dec_bih, Gd, 1024, 0);

    // whole bidirectional encoder + hpost: ONE persistent launch
    enc_persist_kernel<<<dim3(256), 256, 0, stream>>>(
        Gf, Gb, Whh_f, Whh_b, bhh_f, bhh_b, text,
        hF0, hF1, hB0, hB1, E, hpost_W, hpost_b, hd0, bar);

    // In-place ys -> [K|V]: 2 chunks of 16384 rows
    for (int c = 0; c < 2; ++c) {
        const int r0 = c * 16384;
        kv_chunk_kernel<<<dim3(8, 256), 256, 0, stream>>>(
            E, wk_W, wv_W, wk_b, wv_b, T, r0);
        copy4_kernel<<<dim3(4096), 256, 0, stream>>>(
            (float4*)(E + (size_t)r0 * 1024), (const float4*)T,
            16384 * 1024 / 4);
    }

    float* attn = (float*)d_out;                  // (256,64,128)
    float* res  = attn + (size_t)B * LP * LT;     // (256,64,80)

    // whole decoder (initial attend + 64 steps): ONE persistent launch
    dec_persist_kernel<<<dim3(256), 256, 0, stream>>>(
        Gd, dec_Wih, dec_Whh, dec_bhh, E, post_W, post_b,
        attn, res, a_o, dec_i, hd0, hd1, bar + 1);
}

// Round 6
// 11915.820 us; speedup vs baseline: 1.3465x; 1.3465x over previous
//
#include <hip/hip_runtime.h>
#include <math.h>

#define B   256
#define LT  128
#define LP  64
#define DM  512
#define D3  1536
#define DPH 80
#define SCALE_F 0.044194173824159216f   // 1/sqrt(512)

__device__ __forceinline__ float dot4(float4 a, float4 b) {
    return a.x*b.x + a.y*b.y + a.z*b.z + a.w*b.w;
}
__device__ __forceinline__ float sigmoidf_(float x) {
    return 1.0f / (1.0f + expf(-x));
}

// Group barrier among `nblk` blocks sharing counter `cnt`.
// Arrival: RELEASE fetch_add (single wbl2). Poll: RELAXED atomic loads
// (MALL-scoped, NO per-iteration invalidate). Exit: ONE acquire fence.
__device__ __forceinline__ void group_barrier(int* cnt, int target) {
    __syncthreads();
    if (threadIdx.x == 0) {
        __hip_atomic_fetch_add(cnt, 1, __ATOMIC_RELEASE,
                               __HIP_MEMORY_SCOPE_AGENT);
        while (__hip_atomic_load(cnt, __ATOMIC_RELAXED,
                                 __HIP_MEMORY_SCOPE_AGENT) < target)
            __builtin_amdgcn_s_sleep(16);
        __builtin_amdgcn_fence(__ATOMIC_ACQUIRE, "agent");
    }
    __syncthreads();
}

// ---------------------------------------------------------------------------
// Precompute G[r][n] = bias[n] + sum_j Emb[r][j] * W[n*wstride + woff + j]
// ---------------------------------------------------------------------------
__global__ __launch_bounds__(256) void precompG_kernel(
    const float* __restrict__ Emb, const float* __restrict__ W,
    const float* __restrict__ bias, float* __restrict__ G,
    int wstride, int woff)
{
    const int n  = blockIdx.x * 256 + threadIdx.x;
    const int r0 = blockIdx.y * 4;
    __shared__ float es[4][DM];
    for (int i = threadIdx.x; i < 4 * DM; i += 256)
        es[i >> 9][i & 511] = Emb[(r0 + (i >> 9)) * DM + (i & 511)];
    __syncthreads();
    float acc[4] = {0.f, 0.f, 0.f, 0.f};
    const float* wr = &W[(size_t)n * wstride + woff];
    for (int j = 0; j < DM; j += 4) {
        float4 w4 = *(const float4*)&wr[j];
        #pragma unroll
        for (int rr = 0; rr < 4; ++rr) {
            float4 e4 = *(const float4*)&es[rr][j];
            acc[rr] += dot4(e4, w4);
        }
    }
    float bv = bias[n];
    #pragma unroll
    for (int rr = 0; rr < 4; ++rr)
        G[(r0 + rr) * D3 + n] = acc[rr] + bv;
}

// ---------------------------------------------------------------------------
// Persistent encoder: 256 blocks x 512 threads (2 waves/SIMD).
// Block = dir x bblk(4, 64 rows) x jblk(32, 16 cols); low 3 bits of blk =
// (bblk<<1)|dir -> group id (8 groups of 32 blocks, XCD-friendly).
// Whh j-slice LDS-resident. Per step: stage h (dbuf), GEMM+GRU, group
// barrier. Global barrier + fused hpost at the end. ~122 KB LDS, 1 blk/CU.
// ---------------------------------------------------------------------------
__global__ __launch_bounds__(512, 1) void enc_persist_kernel(
    const float* __restrict__ Gf, const float* __restrict__ Gb,
    const float* __restrict__ Whh_f, const float* __restrict__ Whh_b,
    const float* __restrict__ bhh_f, const float* __restrict__ bhh_b,
    const int* __restrict__ text,
    float* __restrict__ hF0, float* __restrict__ hF1,
    float* __restrict__ hB0, float* __restrict__ hB1,
    float* __restrict__ E,
    const float* __restrict__ hpost_W, const float* __restrict__ hpost_b,
    float* __restrict__ hd0, int* __restrict__ bar)
{
    __shared__ float Wl[48][516];     // 99 KB: 3 gates x 16 j-cols, K=512
    __shared__ float As[2][64][36];   // 18.4 KB h staging (dbuf)
    __shared__ float xs[1024];        // hpost staging
    __shared__ float bl[48];

    const int tid  = threadIdx.x;
    const int blk  = blockIdx.x;
    const int dir  = blk & 1;
    const int bblk = (blk >> 1) & 3;
    const int jblk = blk >> 3;
    const int jtile = jblk * 16;
    const int btile = bblk * 64;
    int* cnt = bar + (blk & 7);       // group counter

    const float* G   = dir ? Gb : Gf;
    const float* Whh = dir ? Whh_b : Whh_f;
    const float* bhh = dir ? bhh_b : bhh_f;
    float* h0 = dir ? hB0 : hF0;
    float* h1 = dir ? hB1 : hF1;
    const int yoff = dir ? DM : 0;

    // one-time weight slab: row r = g*16 + jj
    for (int i = tid; i < 48 * 128; i += 512) {
        const int r = i >> 7, c = (i & 127) << 2;
        *(float4*)&Wl[r][c] =
            *(const float4*)&Whh[(size_t)((r >> 4) * DM + jtile + (r & 15)) * DM + c];
    }
    if (tid < 48) bl[tid] = bhh[(tid >> 4) * DM + jtile + (tid & 15)];
    __syncthreads();

    const int jj   = tid & 15;        // j lane
    const int rg   = tid >> 4;        // 32 row groups x 2 rows
    const int lrow = tid >> 3;        // staging row 0..63
    const int lcol = (tid & 7) * 4;   // staging col (1 float4)

    for (int s = 0; s < LT; ++s) {
        const int t = dir ? (LT - 1 - s) : s;
        const float* hin = (s & 1) ? h1 : h0;
        float* hout      = (s & 1) ? h0 : h1;

        float acc[2][3];
        #pragma unroll
        for (int m = 0; m < 2; ++m) {
            acc[m][0] = 0.f; acc[m][1] = 0.f; acc[m][2] = 0.f;
        }

        float4 rA = *(const float4*)&hin[(btile + lrow) * DM + lcol];
        int buf = 0;
        for (int kc = 0; kc < 16; ++kc) {
            *(float4*)&As[buf][lrow][lcol] = rA;
            __syncthreads();
            if (kc < 15)
                rA = *(const float4*)&hin[(btile + lrow) * DM + (kc + 1) * 32 + lcol];
            const int kb = kc * 32;
            #pragma unroll
            for (int c4 = 0; c4 < 8; ++c4) {
                float4 bv0 = *(float4*)&Wl[jj][kb + c4 * 4];
                float4 bv1 = *(float4*)&Wl[16 + jj][kb + c4 * 4];
                float4 bv2 = *(float4*)&Wl[32 + jj][kb + c4 * 4];
                #pragma unroll
                for (int m = 0; m < 2; ++m) {
                    float4 av = *(float4*)&As[buf][rg * 2 + m][c4 * 4];
                    acc[m][0] += dot4(av, bv0);
                    acc[m][1] += dot4(av, bv1);
                    acc[m][2] += dot4(av, bv2);
                }
            }
            buf ^= 1;
            __syncthreads();
        }

        const int j = jtile + jj;
        #pragma unroll
        for (int m = 0; m < 2; ++m) {
            const int b = btile + rg * 2 + m;
            const int c = text[b * LT + t];
            float hr = acc[m][0] + bl[jj];
            float hz = acc[m][1] + bl[16 + jj];
            float hn = acc[m][2] + bl[32 + jj];
            float r = sigmoidf_(G[c * D3 + j] + hr);
            float z = sigmoidf_(G[c * D3 + DM + j] + hz);
            float n = tanhf(G[c * D3 + 2 * DM + j] + r * hn);
            float hp = hin[b * DM + j];
            float hv = (1.f - z) * n + z * hp;
            hout[b * DM + j] = hv;
            E[(size_t)(b * LT + t) * 1024 + yoff + j] = hv;
        }
        if (s < LT - 1) group_barrier(cnt, 32 * (s + 1));
    }

    // full-grid barrier, then fused hpost (block blk -> batch row blk)
    group_barrier(bar + 8, 256);
    {
        const int b = blk;
        for (int i = tid; i < 1024; i += 512) {
            xs[i] = (i < DM) ? hF0[b * DM + i] : hB0[b * DM + (i - DM)];
        }
        __syncthreads();
        if (tid < DM) {
            const float* wr = &hpost_W[tid * 1024];
            float acc = 0.f;
            for (int jx = 0; jx < 1024; jx += 4)
                acc += dot4(*(const float4*)&xs[jx], *(const float4*)&wr[jx]);
            hd0[b * DM + tid] = tanhf(acc + hpost_b[tid]);
        }
    }
}

// ---------------------------------------------------------------------------
// Chunked k/v projection (rows [r0, r0+16384)) -> temp T, then copy4 back.
// ---------------------------------------------------------------------------
__global__ __launch_bounds__(256) void kv_chunk_kernel(
    const float* __restrict__ E,
    const float* __restrict__ wk, const float* __restrict__ wv,
    const float* __restrict__ kb, const float* __restrict__ vb,
    float* __restrict__ T, int r0)
{
    __shared__ float As[64][36];
    __shared__ float Bk[64][36];
    __shared__ float Bv[64][36];
    const int tid = threadIdx.x;
    const int nn = tid & 15, bb = tid >> 4;
    const int ntile = blockIdx.x * 64;
    const int mtile = blockIdx.y * 64;

    float ak[4][4], av_[4][4];
    #pragma unroll
    for (int m = 0; m < 4; ++m)
        #pragma unroll
        for (int i = 0; i < 4; ++i) { ak[m][i] = 0.f; av_[m][i] = 0.f; }

    const int lrow = tid >> 3;
    const int lcol = (tid & 7) * 4;

    for (int k0 = 0; k0 < 1024; k0 += 32) {
        __syncthreads();
        *(float4*)&As[lrow][lcol] =
            *(const float4*)&E[(size_t)(r0 + mtile + lrow) * 1024 + k0 + lcol];
        *(float4*)&As[lrow + 32][lcol] =
            *(const float4*)&E[(size_t)(r0 + mtile + lrow + 32) * 1024 + k0 + lcol];
        *(float4*)&Bk[lrow][lcol] =
            *(const float4*)&wk[(ntile + lrow) * 1024 + k0 + lcol];
        *(float4*)&Bk[lrow + 32][lcol] =
            *(const float4*)&wk[(ntile + lrow + 32) * 1024 + k0 + lcol];
        *(float4*)&Bv[lrow][lcol] =
            *(const float4*)&wv[(ntile + lrow) * 1024 + k0 + lcol];
        *(float4*)&Bv[lrow + 32][lcol] =
            *(const float4*)&wv[(ntile + lrow + 32) * 1024 + k0 + lcol];
        __syncthreads();
        #pragma unroll
        for (int c4 = 0; c4 < 8; ++c4) {
            float4 a4[4], k4[4], v4[4];
            #pragma unroll
            for (int m = 0; m < 4; ++m) a4[m] = *(float4*)&As[bb + 16 * m][c4 * 4];
            #pragma unroll
            for (int i = 0; i < 4; ++i) {
                k4[i] = *(float4*)&Bk[nn + 16 * i][c4 * 4];
                v4[i] = *(float4*)&Bv[nn + 16 * i][c4 * 4];
            }
            #pragma unroll
            for (int m = 0; m < 4; ++m)
                #pragma unroll
                for (int i = 0; i < 4; ++i) {
                    ak[m][i]  += dot4(a4[m], k4[i]);
                    av_[m][i] += dot4(a4[m], v4[i]);
                }
        }
    }
    #pragma unroll
    for (int m = 0; m < 4; ++m) {
        const int lm = mtile + bb + 16 * m;
        #pragma unroll
        for (int i = 0; i < 4; ++i) {
            const int gn = ntile + nn + 16 * i;
            T[(size_t)lm * 1024 + gn]       = ak[m][i]  + kb[gn];
            T[(size_t)lm * 1024 + DM + gn]  = av_[m][i] + vb[gn];
        }
    }
}

__global__ __launch_bounds__(256) void copy4_kernel(
    float4* __restrict__ dst, const float4* __restrict__ src, int n4)
{
    int i = blockIdx.x * 256 + threadIdx.x;
    const int stride = gridDim.x * 256;
    for (; i < n4; i += stride) dst[i] = src[i];
}

// ---------------------------------------------------------------------------
// Attend/post body, identical math to R4 (guards valid for 512 threads;
// summation orders unchanged: QK d-halves over 256 threads, PV l-halves).
// ---------------------------------------------------------------------------
__device__ __forceinline__ void attend_body(
    int b, int tid, const float* __restrict__ q, const float* __restrict__ EKV,
    const float* __restrict__ post_W, const float* __restrict__ post_b,
    float* __restrict__ attn, float* __restrict__ res,
    float* __restrict__ a_o, int* __restrict__ dec_i,
    int s, int attn_row, int do_post, int do_attn,
    float* qs, float* part, float* sarr, float* red, float4 (*pvp)[128])
{
    if (tid < 128)
        *(float4*)&qs[tid * 4] = *(const float4*)&q[b * DM + tid * 4];
    __syncthreads();

    if (do_post) {
        if (tid < DPH) {
            const float* wr = &post_W[tid * DM];
            float acc = 0.f;
            for (int d = 0; d < DM; d += 4)
                acc += dot4(*(const float4*)&qs[d], *(const float4*)&wr[d]);
            float lv = acc + post_b[tid];
            res[(size_t)(b * LP + s) * DPH + tid] = lv;
            part[tid] = lv;
        }
        __syncthreads();
        if (tid == 0) {   // first-occurrence argmax, matching jnp.argmax
            float best = part[0]; int bi = 0;
            for (int p = 1; p < DPH; ++p) {
                float vv = part[p];
                if (vv > best) { best = vv; bi = p; }
            }
            dec_i[b] = bi;
        }
        __syncthreads();
    }

    if (do_attn) {
        if (tid < 256) {
            const int r = tid & 127, half = tid >> 7;
            const float* kr = &EKV[(size_t)(b * LT + r) * 1024 + half * 256];
            const float* qh = &qs[half * 256];
            float p = 0.f;
            #pragma unroll
            for (int d = 0; d < 256; d += 4)
                p += dot4(*(const float4*)&qh[d], *(const float4*)&kr[d]);
            part[tid] = p;
        }
        __syncthreads();
        if (tid < LT) sarr[tid] = (part[tid] + part[tid + 128]) * SCALE_F;
        __syncthreads();
        if (tid < 64) {
            float m = fmaxf(sarr[tid], sarr[tid + 64]);
            #pragma unroll
            for (int off = 32; off > 0; off >>= 1)
                m = fmaxf(m, __shfl_xor(m, off));
            if (tid == 0) red[0] = m;
        }
        __syncthreads();
        const float smax = red[0];
        if (tid < LT) sarr[tid] = expf(sarr[tid] - smax);
        __syncthreads();
        if (tid < 64) {
            float ssum = sarr[tid] + sarr[tid + 64];
            #pragma unroll
            for (int off = 32; off > 0; off >>= 1)
                ssum += __shfl_xor(ssum, off);
            if (tid == 0) red[1] = ssum;
        }
        __syncthreads();
        const float inv = 1.0f / red[1];
        if (tid < LT) {
            float a = sarr[tid] * inv;
            sarr[tid] = a;
            attn[(size_t)(b * LP + attn_row) * LT + tid] = a;
        }
        __syncthreads();
        if (tid < 256) {
            const int d4 = tid & 127, half = tid >> 7;
            const float* vb0 = &EKV[(size_t)b * LT * 1024 + DM];
            float4 acc = make_float4(0.f, 0.f, 0.f, 0.f);
            const int l0 = half * 64;
            #pragma unroll 8
            for (int l = l0; l < l0 + 64; ++l) {
                float a = sarr[l];
                float4 v4 = *(const float4*)&vb0[(size_t)l * 1024 + d4 * 4];
                acc.x += a * v4.x; acc.y += a * v4.y;
                acc.z += a * v4.z; acc.w += a * v4.w;
            }
            pvp[half][d4] = acc;
        }
        __syncthreads();
        if (tid < 128) {
            float4 p0 = pvp[0][tid], p1 = pvp[1][tid];
            float4 o = make_float4(p0.x + p1.x, p0.y + p1.y,
                                   p0.z + p1.z, p0.w + p1.w);
            *(float4*)&a_o[b * DM + tid * 4] = o;
        }
    }
}

// ---------------------------------------------------------------------------
// Persistent decoder: 256 blocks x 512 threads. Block = bblk(4, 64 rows,
// low 2 bits -> group of 64 blocks) x jblk(64, 8 cols). Wih-half + Whh
// slabs LDS-resident. Per step: GRU | grp-barrier | attend+post (row =
// btile+jblk) | grp-barrier. 4 independent groups. ~125 KB LDS, 1 blk/CU.
// ---------------------------------------------------------------------------
__global__ __launch_bounds__(512, 1) void dec_persist_kernel(
    const float* __restrict__ Gd,
    const float* __restrict__ dec_Wih, const float* __restrict__ dec_Whh,
    const float* __restrict__ dec_bhh,
    const float* __restrict__ EKV,
    const float* __restrict__ post_W, const float* __restrict__ post_b,
    float* __restrict__ attn, float* __restrict__ res,
    float* __restrict__ a_o, int* __restrict__ dec_i,
    float* __restrict__ hd0, float* __restrict__ hd1,
    int* __restrict__ bar)
{
    __shared__ float Wi[24][516];     // 3 gates x 8 j-cols, K=512 (a_o part)
    __shared__ float Wh[24][516];     // 3 gates x 8 j-cols, K=512 (h part)
    __shared__ float As[2][64][36];
    __shared__ float bl[24];
    __shared__ float qs[DM];
    __shared__ float part[256];
    __shared__ float sarr[LT];
    __shared__ float red[2];
    __shared__ float4 pvp[2][128];

    const int tid  = threadIdx.x;
    const int blk  = blockIdx.x;
    const int bblk = blk & 3;
    const int jblk = blk >> 2;        // 0..63
    const int jtile = jblk * 8;
    const int btile = bblk * 64;
    const int arow  = btile + jblk;   // this block's attend row
    int* cnt = bar + 9 + bblk;
    int nb = 0;

    for (int i = tid; i < 24 * 128; i += 512) {
        const int r = i >> 7, c = (i & 127) << 2;
        const int wrow = (r >> 3) * DM + jtile + (r & 7);
        *(float4*)&Wi[r][c] =
            *(const float4*)&dec_Wih[(size_t)wrow * 1024 + DM + c];
        *(float4*)&Wh[r][c] =
            *(const float4*)&dec_Whh[(size_t)wrow * DM + c];
    }
    if (tid < 24) bl[tid] = dec_bhh[(tid >> 3) * DM + jtile + (tid & 7)];
    __syncthreads();

    // initial attend: q = hd0 -> attn row 0 + a_o
    attend_body(arow, tid, hd0, EKV, post_W, post_b, attn, res, a_o, dec_i,
                0, 0, 0, 1, qs, part, sarr, red, pvp);
    ++nb; group_barrier(cnt, 64 * nb);

    const int jj   = tid & 7;         // j lane
    const int rr   = tid >> 3;        // row 0..63 (1 row/thread)
    const int lrow = tid >> 3;
    const int lcol = (tid & 7) * 4;

    for (int s = 0; s < LP; ++s) {
        const float* hin = (s & 1) ? hd1 : hd0;
        float* hout      = (s & 1) ? hd0 : hd1;

        float acc[4] = {0.f, 0.f, 0.f, 0.f};   // r, z, inn, hn

        #pragma unroll
        for (int ph = 0; ph < 2; ++ph) {
            const float* Aptr = (ph == 0) ? a_o : hin;
            const float (*W)[516] = (ph == 0) ? Wi : Wh;

            float4 rA = *(const float4*)&Aptr[(btile + lrow) * DM + lcol];
            int buf = 0;
            for (int kc = 0; kc < 16; ++kc) {
                *(float4*)&As[buf][lrow][lcol] = rA;
                __syncthreads();
                if (kc < 15)
                    rA = *(const float4*)&Aptr[(btile + lrow) * DM + (kc + 1) * 32 + lcol];
                const int kb = kc * 32;
                #pragma unroll
                for (int c4 = 0; c4 < 8; ++c4) {
                    float4 bv0 = *(float4*)&W[jj][kb + c4 * 4];
                    float4 bv1 = *(float4*)&W[8 + jj][kb + c4 * 4];
                    float4 bv2 = *(float4*)&W[16 + jj][kb + c4 * 4];
                    float4 av  = *(float4*)&As[buf][rr][c4 * 4];
                    acc[0]      += dot4(av, bv0);
                    acc[1]      += dot4(av, bv1);
                    acc[2 + ph] += dot4(av, bv2);
                }
                buf ^= 1;
                __syncthreads();
            }
        }

        {
            const int j = jtile + jj;
            const int b = btile + rr;
            const int c = dec_i[b];
            float r = sigmoidf_(Gd[c * D3 + j] + bl[jj] + acc[0]);
            float z = sigmoidf_(Gd[c * D3 + DM + j] + bl[8 + jj] + acc[1]);
            float n = tanhf(Gd[c * D3 + 2 * DM + j] + acc[2]
                            + r * (acc[3] + bl[16 + jj]));
            float hp = hin[b * DM + j];
            hout[b * DM + j] = (1.f - z) * n + z * hp;
        }
        ++nb; group_barrier(cnt, 64 * nb);

        attend_body(arow, tid, hout, EKV, post_W, post_b, attn, res, a_o, dec_i,
                    s, s + 1, 1, (s < LP - 1) ? 1 : 0,
                    qs, part, sarr, red, pvp);
        if (s < LP - 1) { ++nb; group_barrier(cnt, 64 * nb); }
    }
}

// ---------------------------------------------------------------------------
extern "C" void kernel_launch(void* const* d_in, const int* in_sizes, int n_in,
                              void* d_out, int out_size, void* d_ws, size_t ws_size,
                              hipStream_t stream)
{
    const int*   text    = (const int*)d_in[0];
    const float* E_alpha = (const float*)d_in[2];
    const float* Wih_f   = (const float*)d_in[3];
    const float* Whh_f   = (const float*)d_in[4];
    const float* bih_f   = (const float*)d_in[5];
    const float* bhh_f   = (const float*)d_in[6];
    const float* Wih_b   = (const float*)d_in[7];
    const float* Whh_b   = (const float*)d_in[8];
    const float* bih_b   = (const float*)d_in[9];
    const float* bhh_b   = (const float*)d_in[10];
    const float* hpost_W = (const float*)d_in[11];
    const float* hpost_b = (const float*)d_in[12];
    const float* wk_W    = (const float*)d_in[13];
    const float* wk_b    = (const float*)d_in[14];
    const float* wv_W    = (const float*)d_in[15];
    const float* wv_b    = (const float*)d_in[16];
    const float* E_ph    = (const float*)d_in[17];
    const float* dec_Wih = (const float*)d_in[18];
    const float* dec_Whh = (const float*)d_in[19];
    const float* dec_bih = (const float*)d_in[20];
    const float* dec_bhh = (const float*)d_in[21];
    const float* post_W  = (const float*)d_in[22];
    const float* post_b  = (const float*)d_in[23];

    float* ws = (float*)d_ws;
    float* Gf  = ws;                 // 100*1536
    float* Gb  = Gf  + 153600;
    float* Gd  = Gb  + 153600;       // 80*1536
    float* hF0 = Gd  + 122880;
    float* hF1 = hF0 + 131072;
    float* hB0 = hF1 + 131072;
    float* hB1 = hB0 + 131072;
    float* hd0 = hB1 + 131072;
    float* hd1 = hd0 + 131072;
    float* a_o = hd1 + 131072;
    int*   dec_i = (int*)(a_o + 131072);
    int*   bar   = dec_i + 256;      // [0..7] enc groups, [8] global, [9..12] dec
    float* E   = a_o + 131072 + 512; // 32768*1024: ys, then in-place K|V
    float* T   = E + 33554432;       // 16384*1024 chunk temp (64 MB)

    hipMemsetAsync(hF0, 0, 131072 * sizeof(float), stream);
    hipMemsetAsync(hB0, 0, 131072 * sizeof(float), stream);
    hipMemsetAsync(dec_i, 0, (256 + 16) * sizeof(int), stream);

    precompG_kernel<<<dim3(6, 25), 256, 0, stream>>>(E_alpha, Wih_f, bih_f, Gf, DM, 0);
    precompG_kernel<<<dim3(6, 25), 256, 0, stream>>>(E_alpha, Wih_b, bih_b, Gb, DM, 0);
    precompG_kernel<<<dim3(6, 20), 256, 0, stream>>>(E_ph, dec_Wih, dec_bih, Gd, 1024, 0);

    // whole bidirectional encoder + hpost: ONE persistent launch
    enc_persist_kernel<<<dim3(256), 512, 0, stream>>>(
        Gf, Gb, Whh_f, Whh_b, bhh_f, bhh_b, text,
        hF0, hF1, hB0, hB1, E, hpost_W, hpost_b, hd0, bar);

    // In-place ys -> [K|V]: 2 chunks of 16384 rows
    for (int c = 0; c < 2; ++c) {
        const int r0 = c * 16384;
        kv_chunk_kernel<<<dim3(8, 256), 256, 0, stream>>>(
            E, wk_W, wv_W, wk_b, wv_b, T, r0);
        copy4_kernel<<<dim3(4096), 256, 0, stream>>>(
            (float4*)(E + (size_t)r0 * 1024), (const float4*)T,
            16384 * 1024 / 4);
    }

    float* attn = (float*)d_out;                  // (256,64,128)
    float* res  = attn + (size_t)B * LP * LT;     // (256,64,80)

    // whole decoder (initial attend + 64 steps): ONE persistent launch
    dec_persist_kernel<<<dim3(256), 512, 0, stream>>>(
        Gd, dec_Wih, dec_Whh, dec_bhh, E, post_W, post_b,
        attn, res, a_o, dec_i, hd0, hd1, bar);
}